// Round 3
// baseline (373.150 us; speedup 1.0000x reference)
//
#include <hip/hip_runtime.h>
#include <math.h>

// GridNeRF fused hierarchical sampling + volume rendering.
// N=65536 rays, NC=64 coarse, NF=128 fine, S=192 combined samples.
//
// R4 (resubmit; R2 bench was a broker acquisition timeout, kernel unmeasured).
// Latency-chain attack. R3 cut VALU instrs 17% with ZERO duration change
// -> not issue-bound; bound by per-wave serial dependency chains (dependent
// shuffle/LDS ops, ~60-120cy each: scans 13, bitonic 21, searches 14, P5 ~14).
// Restructure: TWO rays per wave (32 lanes per ray, segment shuffles width=32).
//  - scans: 5 steps (was 6), cover 2 rays at once
//  - bitonic: 4 regs/lane -> 15 cross-lane stages (was 21), extra stages are
//    in-lane reg min/max (no latency), covers 2 rays
//  - searches: 4 (fine) / 2 (coarse) independent queries per lane -> overlap
//  - final reduce: 5 steps (was 6), 2 rays at once
//  - wave count halves (32768) => total serial chain work per SIMD ~halves.
// Merge-rank sort strategy (validated R2) unchanged:
//  rank(coarse i) = i + #{u < cdf[i]}, rank(fine j) = j + pos_j + 1,
//  cdf forced monotone via max-scan so the scatter bijection is exact.

#define NRAYS 65536
#define NCC   64
#define NFF   128
#define SS    192

struct f3 { float x, y, z; };   // 12 B -> global dwordx3

__global__ __launch_bounds__(256)
void nerf_fused(const float* __restrict__ ro,  const float* __restrict__ rd,
                const float* __restrict__ cw,  const float* __restrict__ ct,
                const float* __restrict__ uu,  const float* __restrict__ col,
                const float* __restrict__ den, float* __restrict__ out)
{
    const int lane = threadIdx.x & 63;
    const int wv   = threadIdx.x >> 6;
    const int half = lane >> 5;          // which ray within the wave
    const int hl   = lane & 31;          // lane within the 32-lane segment
    const int ridx = wv * 2 + half;      // ray slot within block (0..7)
    const int ray  = blockIdx.x * 8 + ridx;

    __shared__ float s_cdf [8][65];      // monotone cdf[0..64] per ray
    __shared__ float s_ct  [8][64];      // coarse t per ray
    __shared__ float s_su  [8][128];     // sorted u per ray
    __shared__ float s_vals[8][192];     // sorted combined t per ray

    // ---------- global loads issued up front (col deferred: biggest reg cost,
    // consumed last, latency hidden by TLP) ----------
    float2 cw2 = *(const float2*)(cw + (size_t)ray * NCC + 2 * hl);
    float2 ct2 = *(const float2*)(ct + (size_t)ray * NCC + 2 * hl);
    float4 u4  = *(const float4*)(uu + (size_t)ray * NFF + 4 * hl);
    float dx = rd[(size_t)ray * 3 + 0], dy = rd[(size_t)ray * 3 + 1], dz = rd[(size_t)ray * 3 + 2];
    float ox = ro[(size_t)ray * 3 + 0], oy = ro[(size_t)ray * 3 + 1], oz = ro[(size_t)ray * 3 + 2];
    const float* dnp = den + (size_t)ray * SS + 6 * hl;
    float2 dnA = *(const float2*)(dnp + 0);
    float2 dnB = *(const float2*)(dnp + 2);
    float2 dnC = *(const float2*)(dnp + 4);

    // ---------- Phase 1: weights -> normalized monotone cdf (2/lane) ----------
    float wt0 = cw2.x + 1e-5f, wt1 = cw2.y + 1e-5f;
    float x = wt0 + wt1;                       // pair sum
    #pragma unroll
    for (int off = 1; off < 32; off <<= 1) {
        float y = __shfl_up(x, off, 32);
        x += (hl >= off) ? y : 0.0f;
    }
    float total = __shfl(x, 31, 32);
    float inv = 1.0f / total;
    float cdfv1 = x * inv;                     // cdf value at element 2hl+1
    float cdfv0 = (x - wt1) * inv;             // cdf value at element 2hl
    // prefix-max for monotonicity (pair max == cdfv1 since cdfv1 >= cdfv0)
    float pm = cdfv1;
    #pragma unroll
    for (int off = 1; off < 32; off <<= 1) {
        float y = __shfl_up(pm, off, 32);
        pm = fmaxf(pm, (hl >= off) ? y : 0.0f);
    }
    float mex = __shfl_up(pm, 1, 32);
    mex = (hl == 0) ? 0.0f : mex;              // max over all earlier pairs
    float c0m = fmaxf(cdfv0, mex);             // monotone cdf[2hl+1]
    float c1m = fmaxf(cdfv1, c0m);             // monotone cdf[2hl+2]
    s_cdf[ridx][2 * hl + 1] = c0m;
    s_cdf[ridx][2 * hl + 2] = c1m;
    if (hl == 0) s_cdf[ridx][0] = 0.0f;
    *(float2*)&s_ct[ridx][2 * hl] = ct2;

    // ---------- Phase 2: bitonic sort of 128 u's, 4 regs/lane, 32 lanes ----------
    float v0 = u4.x, v1 = u4.y, v2 = u4.z, v3 = u4.w;   // elements 4hl+r

#define LSTAGE(m, up) { \
    bool km = ((hl & (m)) == 0) == (up); float p; \
    p = __shfl_xor(v0, (m), 32); v0 = km ? fminf(v0, p) : fmaxf(v0, p); \
    p = __shfl_xor(v1, (m), 32); v1 = km ? fminf(v1, p) : fmaxf(v1, p); \
    p = __shfl_xor(v2, (m), 32); v2 = km ? fminf(v2, p) : fmaxf(v2, p); \
    p = __shfl_xor(v3, (m), 32); v3 = km ? fminf(v3, p) : fmaxf(v3, p); }
#define ISTAGE2(up) { float mn, mx; \
    mn = fminf(v0, v2); mx = fmaxf(v0, v2); v0 = (up) ? mn : mx; v2 = (up) ? mx : mn; \
    mn = fminf(v1, v3); mx = fmaxf(v1, v3); v1 = (up) ? mn : mx; v3 = (up) ? mx : mn; }
#define ISTAGE1(up) { float mn, mx; \
    mn = fminf(v0, v1); mx = fmaxf(v0, v1); v0 = (up) ? mn : mx; v1 = (up) ? mx : mn; \
    mn = fminf(v2, v3); mx = fmaxf(v2, v3); v2 = (up) ? mn : mx; v3 = (up) ? mx : mn; }

    { // k=2: pair (0,1) ascending, (2,3) descending
        float mn = fminf(v0, v1), mx = fmaxf(v0, v1); v0 = mn; v1 = mx;
        mn = fminf(v2, v3); mx = fmaxf(v2, v3); v2 = mx; v3 = mn;
    }
    { bool up = ((hl & 1)  == 0); ISTAGE2(up); ISTAGE1(up); }                 // k=4
    { bool up = ((hl & 2)  == 0); LSTAGE(1, up); ISTAGE2(up); ISTAGE1(up); }  // k=8
    { bool up = ((hl & 4)  == 0); LSTAGE(2, up); LSTAGE(1, up); ISTAGE2(up); ISTAGE1(up); }  // k=16
    { bool up = ((hl & 8)  == 0); LSTAGE(4, up); LSTAGE(2, up); LSTAGE(1, up); ISTAGE2(up); ISTAGE1(up); }  // k=32
    { bool up = ((hl & 16) == 0); LSTAGE(8, up); LSTAGE(4, up); LSTAGE(2, up); LSTAGE(1, up); ISTAGE2(up); ISTAGE1(up); }  // k=64
    { const bool up = true;       LSTAGE(16, up); LSTAGE(8, up); LSTAGE(4, up); LSTAGE(2, up); LSTAGE(1, up); ISTAGE2(up); ISTAGE1(up); }  // k=128

    *(float4*)&s_su[ridx][4 * hl] = make_float4(v0, v1, v2, v3);

    // ---------- Phase 3: fine t + scatter by merge rank (4 queries/lane) ----------
    const float* cdfp = s_cdf[ridx];
    const float* ctp  = s_ct[ridx];
    float us[4] = {v0, v1, v2, v3};
    #pragma unroll
    for (int q = 0; q < 4; ++q) {
        float u = us[q];
        int pos = 0;                           // max{p in [0,63]: cdf[p] <= u}
        #pragma unroll
        for (int st = 32; st >= 1; st >>= 1) {
            int np = pos + st;                 // np in [1,63]
            pos = (cdfp[np] <= u) ? np : pos;
        }
        int above = (pos + 1 < 63) ? (pos + 1) : 63;
        float cb = cdfp[pos], ca = cdfp[above];
        float tb = ctp[pos],  ta = ctp[above];
        float dnm = ca - cb;
        dnm = (dnm < 1e-5f) ? 1.0f : dnm;
        float tt = (u - cb) / dnm;
        float fval = tb + tt * (ta - tb);
        int rank = 4 * hl + q + pos + 1;       // j + #{coarse <= u_j}
        s_vals[ridx][rank] = fval;
    }

    // ---------- Phase 4: coarse merge rank + scatter (2 keys/lane) ----------
    // keys cdf[2hl], cdf[2hl+1] come from registers (one segment shuffle)
    const float* sup = s_su[ridx];
    float keyhi = c0m;                          // cdf[2hl+1]
    float keylo = __shfl_up(c1m, 1, 32);        // cdf[2hl] = prev lane's cdf[2hl'+2]
    keylo = (hl == 0) ? 0.0f : keylo;
    int cnt0 = 0, cnt1 = 0;                     // #{u < key}
    #pragma unroll
    for (int st = 128; st >= 1; st >>= 1) {
        int np0 = cnt0 + st; bool ok0 = (np0 <= 128) && (sup[np0 - 1] < keylo); cnt0 = ok0 ? np0 : cnt0;
        int np1 = cnt1 + st; bool ok1 = (np1 <= 128) && (sup[np1 - 1] < keyhi); cnt1 = ok1 ? np1 : cnt1;
    }
    s_vals[ridx][2 * hl     + cnt0] = ct2.x;
    s_vals[ridx][2 * hl + 1 + cnt1] = ct2.y;

    // ---------- Phase 5: volume rendering, 6 samples/lane, 32 lanes/ray ----------
    float2 a01 = *(const float2*)&s_vals[ridx][6 * hl + 0];
    float2 a23 = *(const float2*)&s_vals[ridx][6 * hl + 2];
    float2 a45 = *(const float2*)&s_vals[ridx][6 * hl + 4];
    float sv[6] = {a01.x, a01.y, a23.x, a23.y, a45.x, a45.y};

    float nrm = sqrtf(dx * dx + dy * dy + dz * dz);
    float tnext = __shfl_down(sv[0], 1, 32);    // t[6(hl+1)]
    float dd[6];
    dd[0] = sv[1] - sv[0];
    dd[1] = sv[2] - sv[1];
    dd[2] = sv[3] - sv[2];
    dd[3] = sv[4] - sv[3];
    dd[4] = sv[5] - sv[4];
    dd[5] = (hl == 31) ? 1e10f : (tnext - sv[5]);

    float dnv[6] = {dnA.x, dnA.y, dnB.x, dnB.y, dnC.x, dnC.y};
    float aa[6], ffv[6];
    #pragma unroll
    for (int r = 0; r < 6; ++r) {
        float e = __expf(-dnv[r] * (dd[r] * nrm));
        aa[r]  = 1.0f - e;                      // alpha
        ffv[r] = e + 1e-10f;                    // 1 - alpha + 1e-10
    }

    // fine_points: 18 contiguous floats per lane
    {
        float* fp = out + (size_t)5 * NRAYS + (size_t)ray * (SS * 3) + 18 * hl;
        #pragma unroll
        for (int r = 0; r < 6; ++r) {
            f3 p = {ox + dx * sv[r], oy + dy * sv[r], oz + dz * sv[r]};
            ((f3*)fp)[r] = p;
        }
    }

    // exclusive cumprod over 192 (in-lane 6-prefix + 5-step segment scan)
    float pr1 = ffv[0];
    float pr2 = pr1 * ffv[1];
    float pr3 = pr2 * ffv[2];
    float pr4 = pr3 * ffv[3];
    float pr5 = pr4 * ffv[4];
    float sx  = pr5 * ffv[5];
    #pragma unroll
    for (int off = 1; off < 32; off <<= 1) {
        float y = __shfl_up(sx, off, 32);
        sx *= (hl >= off) ? y : 1.0f;
    }
    float excl = __shfl_up(sx, 1, 32);
    excl = (hl == 0) ? 1.0f : excl;
    float w0 = aa[0] * excl;
    float w1 = aa[1] * (excl * pr1);
    float w2 = aa[2] * (excl * pr2);
    float w3 = aa[3] * (excl * pr3);
    float w4 = aa[4] * (excl * pr4);
    float w5 = aa[5] * (excl * pr5);

    // colors loaded late (streaming; latency hidden by TLP)
    const f3* cp = (const f3*)(col + (size_t)ray * (SS * 3) + 18 * hl);
    f3 c0 = cp[0], c1 = cp[1], c2 = cp[2], c3 = cp[3], c4 = cp[4], c5 = cp[5];

    float rr  = w0*c0.x + w1*c1.x + w2*c2.x + w3*c3.x + w4*c4.x + w5*c5.x;
    float gg  = w0*c0.y + w1*c1.y + w2*c2.y + w3*c3.y + w4*c4.y + w5*c5.y;
    float bb  = w0*c0.z + w1*c1.z + w2*c2.z + w3*c3.z + w4*c4.z + w5*c5.z;
    float dep = w0*sv[0] + w1*sv[1] + w2*sv[2] + w3*sv[3] + w4*sv[4] + w5*sv[5];
    float opa = w0 + w1 + w2 + w3 + w4 + w5;

    #pragma unroll
    for (int off = 16; off >= 1; off >>= 1) {
        rr  += __shfl_xor(rr,  off, 32);
        gg  += __shfl_xor(gg,  off, 32);
        bb  += __shfl_xor(bb,  off, 32);
        dep += __shfl_xor(dep, off, 32);
        opa += __shfl_xor(opa, off, 32);
    }
    if (hl == 0) {
        out[(size_t)ray * 3 + 0] = rr;
        out[(size_t)ray * 3 + 1] = gg;
        out[(size_t)ray * 3 + 2] = bb;
        out[(size_t)3 * NRAYS + ray] = dep;
        out[(size_t)4 * NRAYS + ray] = opa;
    }
#undef LSTAGE
#undef ISTAGE2
#undef ISTAGE1
}

extern "C" void kernel_launch(void* const* d_in, const int* in_sizes, int n_in,
                              void* d_out, int out_size, void* d_ws, size_t ws_size,
                              hipStream_t stream) {
    const float* ro  = (const float*)d_in[0];
    const float* rd  = (const float*)d_in[1];
    const float* cw  = (const float*)d_in[2];
    const float* ct  = (const float*)d_in[3];
    const float* uu  = (const float*)d_in[4];
    const float* col = (const float*)d_in[5];
    const float* den = (const float*)d_in[6];
    float* out = (float*)d_out;
    (void)in_sizes; (void)n_in; (void)out_size; (void)d_ws; (void)ws_size;
    nerf_fused<<<NRAYS / 8, 256, 0, stream>>>(ro, rd, cw, ct, uu, col, den, out);
}